// Round 6
// baseline (167.020 us; speedup 1.0000x reference)
//
#include <hip/hip_runtime.h>
#include <hip/hip_bf16.h>

// C[M,N] = A[M,K] * B[K,N]; M=262144, K=N=128; fp32 in/out, bf16 MFMA.
// Memory-bound. Round-6: revert NT-load experiment (regressed); keep round-3
// structure (8 waves/block, one LDS stage + one barrier, 2 tiles/block,
// grid=512, NT C-stores) and add TRANSPOSED-OPERAND MFMA:
//   mfma(B_frag, A_frag) computes the C-tile transposed, which lands each
//   reg-quad on 4 CONSECUTIVE n-columns -> float4 stores (16 per tile) instead
//   of 64 scalar stores per lane.

typedef __bf16 bf16x8 __attribute__((ext_vector_type(8)));
typedef float  f32x16 __attribute__((ext_vector_type(16)));
typedef float  f32x4  __attribute__((ext_vector_type(4)));
typedef unsigned short ushortx8 __attribute__((ext_vector_type(8)));

#define M_TOTAL (64 * 4096)       // 262144 rows
#define KDIM 128
#define NDIM 128
#define TPB 512                   // 8 waves
#define BM 256                    // rows per tile (8 waves x 32 rows)
#define GRID 512                  // blocks; each does 2 tiles
#define TILES_PER_BLK 2

// Fragment (tile, lane, reg) holds B[k][n]:
//   n = (tile&3)*32 + (lane&31),  k = (tile>>2)*16 + (lane>>5)*8 + reg
// This is simultaneously a valid MFMA B-operand for B and a valid MFMA
// A-operand for B^T (the layouts coincide).
__global__ __launch_bounds__(256) void pack_b_kernel(
    const float* __restrict__ Emb, ushortx8* __restrict__ Bp) {
  const int f    = blockIdx.x * 256 + threadIdx.x;   // 0..2047
  const int tile = f >> 6;
  const int lane = f & 63;
  const int n  = ((tile & 3) << 5) + (lane & 31);
  const int k0 = ((tile >> 2) << 4) + ((lane >> 5) << 3);
  ushortx8 frag;
#pragma unroll
  for (int r = 0; r < 8; ++r) {
    __bf16 h = (__bf16)Emb[(k0 + r) * NDIM + n];
    frag[r] = *(unsigned short*)&h;
  }
  Bp[f] = frag;
}

__device__ __forceinline__ bf16x8 cvt_frag(const float4 a0, const float4 a1) {
  bf16x8 af;
  af[0] = (__bf16)a0.x; af[1] = (__bf16)a0.y;
  af[2] = (__bf16)a0.z; af[3] = (__bf16)a0.w;
  af[4] = (__bf16)a1.x; af[5] = (__bf16)a1.y;
  af[6] = (__bf16)a1.z; af[7] = (__bf16)a1.w;
  return af;
}

__global__ __launch_bounds__(TPB) void emb_gemm_kernel(
    const float* __restrict__ A, const ushortx8* __restrict__ Bp,
    float* __restrict__ C) {
  __shared__ ushortx8 lds_b[2048];   // 32 KiB, linear fragment order

  const int tid = threadIdx.x;

  // ---- DMA-stage packed B -> LDS (linear, conflict-free, async) ----
#pragma unroll
  for (int i = 0; i < 4; ++i) {
    const int c = i * TPB + tid;
    __builtin_amdgcn_global_load_lds(
        (const __attribute__((address_space(1))) void*)(Bp + c),
        (__attribute__((address_space(3))) void*)(&lds_b[c]),
        16, 0, 0);
  }

  const int lane    = tid & 63;
  const int wave    = tid >> 6;            // 0..7
  const int colhalf = lane >> 5;
  const int koff    = colhalf * 8;         // k-offset within 16-wide k-step
  const bf16x8* bbase = (const bf16x8*)lds_b;

  // Prefetch tile 0 first-half A (kk=0..3): overlaps the stage DMA latency.
  const int rbase = wave * 32 + (lane & 31);
  const float* ap0 = A + (size_t)(blockIdx.x * BM + rbase) * KDIM + koff;
  float4 apre[8];
#pragma unroll
  for (int kk = 0; kk < 4; ++kk) {
    apre[kk * 2]     = *(const float4*)(ap0 + kk * 16);
    apre[kk * 2 + 1] = *(const float4*)(ap0 + kk * 16 + 4);
  }

  __syncthreads();   // one barrier for the whole kernel: stage DMA complete

#pragma unroll 1
  for (int it = 0; it < TILES_PER_BLK; ++it) {
    const int mt  = blockIdx.x + it * GRID;          // tile index
    const int row0 = mt * BM + wave * 32;
    const float* ap = A + (size_t)(row0 + (lane & 31)) * KDIM + koff;

    f32x16 acc0 = {}, acc1 = {}, acc2 = {}, acc3 = {};

    // Transposed-operand MFMA: D = B_frag^T-role x A_frag = (C tile)^T.
    // kk = 0..3 from prefetch regs
#pragma unroll
    for (int kk = 0; kk < 4; ++kk) {
      const bf16x8 af = cvt_frag(apre[kk * 2], apre[kk * 2 + 1]);
      const int tb = (kk * 4) * 64 + lane;
      acc0 = __builtin_amdgcn_mfma_f32_32x32x16_bf16(bbase[tb +   0], af, acc0, 0, 0, 0);
      acc1 = __builtin_amdgcn_mfma_f32_32x32x16_bf16(bbase[tb +  64], af, acc1, 0, 0, 0);
      acc2 = __builtin_amdgcn_mfma_f32_32x32x16_bf16(bbase[tb + 128], af, acc2, 0, 0, 0);
      acc3 = __builtin_amdgcn_mfma_f32_32x32x16_bf16(bbase[tb + 192], af, acc3, 0, 0, 0);
    }

    // kk = 4..7 loaded inline
#pragma unroll
    for (int kk = 4; kk < 8; ++kk) {
      const float4 a0 = *(const float4*)(ap + kk * 16);
      const float4 a1 = *(const float4*)(ap + kk * 16 + 4);
      const bf16x8 af = cvt_frag(a0, a1);
      const int tb = (kk * 4) * 64 + lane;
      acc0 = __builtin_amdgcn_mfma_f32_32x32x16_bf16(bbase[tb +   0], af, acc0, 0, 0, 0);
      acc1 = __builtin_amdgcn_mfma_f32_32x32x16_bf16(bbase[tb +  64], af, acc1, 0, 0, 0);
      acc2 = __builtin_amdgcn_mfma_f32_32x32x16_bf16(bbase[tb + 128], af, acc2, 0, 0, 0);
      acc3 = __builtin_amdgcn_mfma_f32_32x32x16_bf16(bbase[tb + 192], af, acc3, 0, 0, 0);
    }

    // Issue NEXT tile's first-half A loads now, overlapping the store drain.
    if (it + 1 < TILES_PER_BLK) {
      const float* apn = A + (size_t)((mt + GRID) * BM + rbase) * KDIM + koff;
#pragma unroll
      for (int kk = 0; kk < 4; ++kk) {
        apre[kk * 2]     = *(const float4*)(apn + kk * 16);
        apre[kk * 2 + 1] = *(const float4*)(apn + kk * 16 + 4);
      }
    }

    // Transposed D layout: lane holds C[row0 + (lane&31)]
    //   [ntile*32 + (r&3) + 8*(r>>2) + 4*colhalf]  -> reg-quads are 4
    // consecutive columns: float4 NT stores, 16 per tile.
    float* crow = C + (size_t)(row0 + (lane & 31)) * NDIM + (colhalf << 2);
#pragma unroll
    for (int q = 0; q < 4; ++q) {
      const f32x4 v0 = {acc0[4 * q], acc0[4 * q + 1], acc0[4 * q + 2], acc0[4 * q + 3]};
      const f32x4 v1 = {acc1[4 * q], acc1[4 * q + 1], acc1[4 * q + 2], acc1[4 * q + 3]};
      const f32x4 v2 = {acc2[4 * q], acc2[4 * q + 1], acc2[4 * q + 2], acc2[4 * q + 3]};
      const f32x4 v3 = {acc3[4 * q], acc3[4 * q + 1], acc3[4 * q + 2], acc3[4 * q + 3]};
      __builtin_nontemporal_store(v0, (f32x4*)(crow + q * 8 +  0));
      __builtin_nontemporal_store(v1, (f32x4*)(crow + q * 8 + 32));
      __builtin_nontemporal_store(v2, (f32x4*)(crow + q * 8 + 64));
      __builtin_nontemporal_store(v3, (f32x4*)(crow + q * 8 + 96));
    }
  }
}

extern "C" void kernel_launch(void* const* d_in, const int* in_sizes, int n_in,
                              void* d_out, int out_size, void* d_ws, size_t ws_size,
                              hipStream_t stream) {
  const float* A   = (const float*)d_in[0];   // inputs  (B,S,I) fp32
  const float* Emb = (const float*)d_in[1];   // embedding (I,E) fp32
  float* out = (float*)d_out;                 // (B,S,E) fp32
  ushortx8* Bp = (ushortx8*)d_ws;             // 32 KiB packed B fragments

  pack_b_kernel<<<dim3(8), dim3(256), 0, stream>>>(Emb, Bp);
  emb_gemm_kernel<<<dim3(GRID), dim3(TPB), 0, stream>>>(A, Bp, out);
}

// Round 7
// 44.605 us; speedup vs baseline: 3.7444x; 3.7444x over previous
//
#include <hip/hip_runtime.h>
#include <hip/hip_bf16.h>

// C[M,N] = A[M,K] * B[K,N]; M=262144, K=N=128; fp32 in/out, bf16 MFMA.
// Memory-bound. Round-7: revert transposed-store experiment (WRITE_SIZE +83%:
// NT stores of scattered 16B segments hit HBM as partial lines). Back to the
// round-3 structure (scalar NT stores = 2x128B contiguous per wave instr),
// and fold the B-pack INTO the gemm kernel: each block gathers the 64 KB
// fp32 embedding (L2/L3-hot) straight into LDS fragments with conflict-free
// linear ds_write_b128 — removes the pack dispatch + graph dependency gap.

typedef __bf16 bf16x8 __attribute__((ext_vector_type(8)));
typedef float  f32x16 __attribute__((ext_vector_type(16)));
typedef unsigned short ushortx8 __attribute__((ext_vector_type(8)));

#define M_TOTAL (64 * 4096)       // 262144 rows
#define KDIM 128
#define NDIM 128
#define TPB 512                   // 8 waves
#define BM 256                    // rows per tile (8 waves x 32 rows)
#define GRID 512                  // blocks; each does 2 tiles
#define TILES_PER_BLK 2

__device__ __forceinline__ bf16x8 cvt_frag(const float4 a0, const float4 a1) {
  bf16x8 af;
  af[0] = (__bf16)a0.x; af[1] = (__bf16)a0.y;
  af[2] = (__bf16)a0.z; af[3] = (__bf16)a0.w;
  af[4] = (__bf16)a1.x; af[5] = (__bf16)a1.y;
  af[6] = (__bf16)a1.z; af[7] = (__bf16)a1.w;
  return af;
}

__global__ __launch_bounds__(TPB) void emb_gemm_kernel(
    const float* __restrict__ A, const float* __restrict__ Emb,
    float* __restrict__ C) {
  // B fragments, bf16, MFMA operand order. Fragment f=(tile,lane) holds
  // B[k][n]: n=(tile&3)*32+(lane&31), k=(tile>>2)*16+(lane>>5)*8+reg.
  __shared__ ushortx8 lds_b[2048];   // 32 KiB, linear fragment order

  const int tid     = threadIdx.x;
  const int lane    = tid & 63;
  const int wave    = tid >> 6;            // 0..7
  const int colhalf = lane >> 5;
  const int koff    = colhalf * 8;         // k-offset within 16-wide k-step
  const int rbase   = wave * 32 + (lane & 31);

  // ---- Issue tile-0 A prefetch FIRST (longest latency: HBM) ----
  const float* ap0 = A + (size_t)(blockIdx.x * BM + rbase) * KDIM + koff;
  float4 apre[8];
#pragma unroll
  for (int kk = 0; kk < 4; ++kk) {
    apre[kk * 2]     = *(const float4*)(ap0 + kk * 16);
    apre[kk * 2 + 1] = *(const float4*)(ap0 + kk * 16 + 4);
  }

  // ---- In-kernel B staging: gather Emb (64 KB, L2/L3-hot) -> LDS frags ----
  // 4 fragments per thread; gathers are scalar (column of 8, stride 512 B)
  // but L2-hit; ds_write_b128 at linear f*16 B is the canonical
  // conflict-free pattern.
  float bval[4][8];
#pragma unroll
  for (int i = 0; i < 4; ++i) {
    const int f    = tid + i * TPB;
    const int tile = f >> 6;
    const int fl   = f & 63;
    const int n    = ((tile & 3) << 5) + (fl & 31);
    const int k0   = ((tile >> 2) << 4) + ((fl >> 5) << 3);
    const float* ep = Emb + k0 * NDIM + n;
#pragma unroll
    for (int r = 0; r < 8; ++r) bval[i][r] = ep[r * NDIM];
  }
#pragma unroll
  for (int i = 0; i < 4; ++i) {
    const int f = tid + i * TPB;
    ushortx8 frag;
#pragma unroll
    for (int r = 0; r < 8; ++r) {
      __bf16 h = (__bf16)bval[i][r];
      frag[r] = *(unsigned short*)&h;
    }
    lds_b[f] = frag;
  }

  __syncthreads();   // one barrier: B staged (and A prefetch drained)

  const bf16x8* bbase = (const bf16x8*)lds_b;

#pragma unroll 1
  for (int it = 0; it < TILES_PER_BLK; ++it) {
    const int mt   = blockIdx.x + it * GRID;         // tile index
    const int row0 = mt * BM + wave * 32;
    const float* ap = A + (size_t)(row0 + (lane & 31)) * KDIM + koff;

    f32x16 acc0 = {}, acc1 = {}, acc2 = {}, acc3 = {};

    // kk = 0..3 from prefetch regs
#pragma unroll
    for (int kk = 0; kk < 4; ++kk) {
      const bf16x8 af = cvt_frag(apre[kk * 2], apre[kk * 2 + 1]);
      const int tb = (kk * 4) * 64 + lane;
      acc0 = __builtin_amdgcn_mfma_f32_32x32x16_bf16(af, bbase[tb +   0], acc0, 0, 0, 0);
      acc1 = __builtin_amdgcn_mfma_f32_32x32x16_bf16(af, bbase[tb +  64], acc1, 0, 0, 0);
      acc2 = __builtin_amdgcn_mfma_f32_32x32x16_bf16(af, bbase[tb + 128], acc2, 0, 0, 0);
      acc3 = __builtin_amdgcn_mfma_f32_32x32x16_bf16(af, bbase[tb + 192], acc3, 0, 0, 0);
    }

    // kk = 4..7 loaded inline
#pragma unroll
    for (int kk = 4; kk < 8; ++kk) {
      const float4 a0 = *(const float4*)(ap + kk * 16);
      const float4 a1 = *(const float4*)(ap + kk * 16 + 4);
      const bf16x8 af = cvt_frag(a0, a1);
      const int tb = (kk * 4) * 64 + lane;
      acc0 = __builtin_amdgcn_mfma_f32_32x32x16_bf16(af, bbase[tb +   0], acc0, 0, 0, 0);
      acc1 = __builtin_amdgcn_mfma_f32_32x32x16_bf16(af, bbase[tb +  64], acc1, 0, 0, 0);
      acc2 = __builtin_amdgcn_mfma_f32_32x32x16_bf16(af, bbase[tb + 128], acc2, 0, 0, 0);
      acc3 = __builtin_amdgcn_mfma_f32_32x32x16_bf16(af, bbase[tb + 192], acc3, 0, 0, 0);
    }

    // Issue NEXT tile's first-half A loads now, overlapping the store drain.
    if (it + 1 < TILES_PER_BLK) {
      const float* apn = A + (size_t)((mt + GRID) * BM + rbase) * KDIM + koff;
#pragma unroll
      for (int kk = 0; kk < 4; ++kk) {
        apre[kk * 2]     = *(const float4*)(apn + kk * 16);
        apre[kk * 2 + 1] = *(const float4*)(apn + kk * 16 + 4);
      }
    }

    // C layout (32x32 MFMA): col = lane&31, row = (reg&3)+8*(reg>>2)+4*colhalf
    // Per store instruction the wave writes 2x128B contiguous segments. NT:
    // C is write-once, keep it from evicting A in L2/L3.
    float* c0 = C + (size_t)row0 * NDIM + (lane & 31);
#pragma unroll
    for (int reg = 0; reg < 16; ++reg) {
      const int r = (reg & 3) + ((reg >> 2) << 3) + (colhalf << 2);
      float* cr = c0 + (size_t)r * NDIM;
      __builtin_nontemporal_store(acc0[reg], cr + 0);
      __builtin_nontemporal_store(acc1[reg], cr + 32);
      __builtin_nontemporal_store(acc2[reg], cr + 64);
      __builtin_nontemporal_store(acc3[reg], cr + 96);
    }
  }
}

extern "C" void kernel_launch(void* const* d_in, const int* in_sizes, int n_in,
                              void* d_out, int out_size, void* d_ws, size_t ws_size,
                              hipStream_t stream) {
  const float* A   = (const float*)d_in[0];   // inputs  (B,S,I) fp32
  const float* Emb = (const float*)d_in[1];   // embedding (I,E) fp32
  float* out = (float*)d_out;                 // (B,S,E) fp32

  emb_gemm_kernel<<<dim3(GRID), dim3(TPB), 0, stream>>>(A, Emb, out);
}